// Round 1
// baseline (936.453 us; speedup 1.0000x reference)
//
#include <hip/hip_runtime.h>

// Shapes from reference
#define Bn   4
#define Cn   720
#define Hn   128
#define Wn   128
#define Pn   9
#define OFFn 80           // Cn / Pn
#define HWn  16384        // Hn * Wn

__global__ __launch_bounds__(256) void dcn_bilinear_kernel(
    const float* __restrict__ x,
    const float* __restrict__ loc,
    const float* __restrict__ bias,
    float* __restrict__ out)
{
    const int pos = blockIdx.x * 256 + threadIdx.x;   // spatial position in [0, HW)
    const int bp  = blockIdx.y;                       // b * P + p
    const int b   = bp / Pn;
    const int p   = bp - b * Pn;

    // Stage this group's 80 bias values into LDS (uniform broadcast reads later).
    __shared__ float sbias[OFFn];
    if (threadIdx.x < OFFn) sbias[threadIdx.x] = bias[p * OFFn + threadIdx.x];
    __syncthreads();

    // location layout: (B, 2P, H, W); channel 2p = y, 2p+1 = x
    const float yq = loc[(b * (2 * Pn) + 2 * p)     * HWn + pos];
    const float xq = loc[(b * (2 * Pn) + 2 * p + 1) * HWn + pos];

    const float y0f = floorf(yq);
    const float x0f = floorf(xq);
    const float dy  = yq - y0f;
    const float dx  = xq - x0f;
    const int y0 = (int)y0f;
    const int x0 = (int)x0f;
    const int y1 = y0 + 1;
    const int x1 = x0 + 1;

    const bool vy0 = (y0 >= 0) && (y0 < Hn);
    const bool vy1 = (y1 >= 0) && (y1 < Hn);
    const bool vx0 = (x0 >= 0) && (x0 < Wn);
    const bool vx1 = (x1 >= 0) && (x1 < Wn);

    const int cy0 = min(max(y0, 0), Hn - 1);
    const int cy1 = min(max(y1, 0), Hn - 1);
    const int cx0 = min(max(x0, 0), Wn - 1);
    const int cx1 = min(max(x1, 0), Wn - 1);

    const float w00 = (vy0 && vx0) ? (1.f - dy) * (1.f - dx) : 0.f;
    const float w01 = (vy0 && vx1) ? (1.f - dy) * dx         : 0.f;
    const float w10 = (vy1 && vx0) ? dy * (1.f - dx)         : 0.f;
    const float w11 = (vy1 && vx1) ? dy * dx                 : 0.f;

    const int i00 = cy0 * Wn + cx0;
    const int i01 = cy0 * Wn + cx1;
    const int i10 = cy1 * Wn + cx0;
    const int i11 = cy1 * Wn + cx1;

    // Base of this (b, p) channel group
    const int base = (b * Cn + p * OFFn) * HWn;
    const float* xb = x + base;
    float* ob = out + base + pos;

    #pragma unroll 4
    for (int c = 0; c < OFFn; ++c) {
        const float v = w00 * xb[i00] + w01 * xb[i01]
                      + w10 * xb[i10] + w11 * xb[i11];
        *ob = v + sbias[c];
        xb += HWn;
        ob += HWn;
    }
}

extern "C" void kernel_launch(void* const* d_in, const int* in_sizes, int n_in,
                              void* d_out, int out_size, void* d_ws, size_t ws_size,
                              hipStream_t stream)
{
    const float* x    = (const float*)d_in[0];
    const float* loc  = (const float*)d_in[1];
    const float* bias = (const float*)d_in[2];
    float* out        = (float*)d_out;

    dim3 grid(HWn / 256, Bn * Pn);   // 64 x 36 = 2304 blocks
    dcn_bilinear_kernel<<<grid, 256, 0, stream>>>(x, loc, bias, out);
}

// Round 2
// 333.303 us; speedup vs baseline: 2.8096x; 2.8096x over previous
//
#include <hip/hip_runtime.h>

// Shapes from reference
#define Bn   4
#define Cn   720
#define Hn   128
#define Wn   128
#define Pn   9
#define OFFn 80           // Cn / Pn
#define HWn  16384        // Hn * Wn
#define TPB  512          // threads per block

// One block per (b, c): stage plane x[b,c,:,:] (64 KB) into LDS coalesced,
// then gather 4 corners per spatial position from LDS. 64 KB LDS -> 2
// blocks/CU (16 waves/CU). x is read from HBM exactly once, coalesced.
__global__ __launch_bounds__(TPB) void dcn_bilinear_lds_kernel(
    const float* __restrict__ x,
    const float* __restrict__ loc,
    const float* __restrict__ bias,
    float* __restrict__ out)
{
    __shared__ float splane[HWn];   // 64 KB

    const int bc = blockIdx.x;        // b * Cn + c
    const int b  = bc / Cn;
    const int c  = bc - b * Cn;       // global channel
    const int p  = c / OFFn;          // group index

    const int tid = threadIdx.x;

    // ---- Stage the 64 KB plane into LDS, float4-coalesced ----
    {
        const float4* src = (const float4*)(x + (size_t)bc * HWn);
        float4* dst = (float4*)splane;
        #pragma unroll
        for (int k = 0; k < HWn / 4 / TPB; ++k) {       // 8 iterations
            dst[tid + k * TPB] = src[tid + k * TPB];
        }
    }
    __syncthreads();

    const float bv = bias[c];
    const float* locy = loc + ((size_t)b * (2 * Pn) + 2 * p)     * HWn;
    const float* locx = loc + ((size_t)b * (2 * Pn) + 2 * p + 1) * HWn;
    float* ob = out + (size_t)bc * HWn;

    // ---- Gather: each thread handles HWn/TPB = 32 positions ----
    #pragma unroll 4
    for (int k = 0; k < HWn / TPB; ++k) {
        const int pos = tid + k * TPB;

        const float yq = locy[pos];
        const float xq = locx[pos];

        const float y0f = floorf(yq);
        const float x0f = floorf(xq);
        const float dy  = yq - y0f;
        const float dx  = xq - x0f;
        const int y0 = (int)y0f;
        const int x0 = (int)x0f;
        const int y1 = y0 + 1;
        const int x1 = x0 + 1;

        const bool vy0 = (y0 >= 0) && (y0 < Hn);
        const bool vy1 = (y1 >= 0) && (y1 < Hn);
        const bool vx0 = (x0 >= 0) && (x0 < Wn);
        const bool vx1 = (x1 >= 0) && (x1 < Wn);

        const int cy0 = min(max(y0, 0), Hn - 1);
        const int cy1 = min(max(y1, 0), Hn - 1);
        const int cx0 = min(max(x0, 0), Wn - 1);
        const int cx1 = min(max(x1, 0), Wn - 1);

        const float w00 = (vy0 && vx0) ? (1.f - dy) * (1.f - dx) : 0.f;
        const float w01 = (vy0 && vx1) ? (1.f - dy) * dx         : 0.f;
        const float w10 = (vy1 && vx0) ? dy * (1.f - dx)         : 0.f;
        const float w11 = (vy1 && vx1) ? dy * dx                 : 0.f;

        const float v00 = splane[cy0 * Wn + cx0];
        const float v01 = splane[cy0 * Wn + cx1];
        const float v10 = splane[cy1 * Wn + cx0];
        const float v11 = splane[cy1 * Wn + cx1];

        ob[pos] = w00 * v00 + w01 * v01 + w10 * v10 + w11 * v11 + bv;
    }
}

extern "C" void kernel_launch(void* const* d_in, const int* in_sizes, int n_in,
                              void* d_out, int out_size, void* d_ws, size_t ws_size,
                              hipStream_t stream)
{
    const float* x    = (const float*)d_in[0];
    const float* loc  = (const float*)d_in[1];
    const float* bias = (const float*)d_in[2];
    float* out        = (float*)d_out;

    dim3 grid(Bn * Cn);   // 2880 blocks, one per (b, channel)
    dcn_bilinear_lds_kernel<<<grid, TPB, 0, stream>>>(x, loc, bias, out);
}